// Round 6
// baseline (560.395 us; speedup 1.0000x reference)
//
#include <hip/hip_runtime.h>
#include <hip/hip_bf16.h>

#define NTOK   4096
#define DMODEL 1024
#define DFF    4096
#define NEXP   8
#define TOPK   2
#define BM 128
#define BN 128
#define BK 32
#define NSLOT   (NTOK*TOPK)            // 8192
#define MAXSLOT (NSLOT + NEXP*BM)      // 9216
#define MAXTILE (MAXSLOT/BM)           // 72

typedef __attribute__((ext_vector_type(8))) short bf16x8;
typedef __attribute__((ext_vector_type(8))) unsigned short u16x8;
typedef __attribute__((ext_vector_type(4))) float f32x4;

__device__ __forceinline__ unsigned short f2bf(float f){
    union { float f; unsigned int u; } v; v.f = f;
    unsigned int r = (v.u + 0x7fffu + ((v.u >> 16) & 1u)) >> 16;
    return (unsigned short)r;
}

__device__ __forceinline__ void gload16(const unsigned short* g, unsigned short* l){
    __builtin_amdgcn_global_load_lds(
        (const __attribute__((address_space(1))) void*)g,
        (__attribute__((address_space(3))) void*)l,
        16, 0, 0);
}

#define WAITLGKM() asm volatile("s_waitcnt lgkmcnt(0)" ::: "memory")
#define WAITVM4()  asm volatile("s_waitcnt vmcnt(4)" ::: "memory")
#define WAITVM0()  asm volatile("s_waitcnt vmcnt(0)" ::: "memory")
#define SCHEDPIN() __builtin_amdgcn_sched_barrier(0)
#define MFMA16(a,b,c) __builtin_amdgcn_mfma_f32_16x16x32_bf16(a,b,c,0,0,0)

// ------ fp32 [E][R][C] -> bf16 [E][C][R] transpose-convert ------
__global__ __launch_bounds__(256) void k_transpose_convert(const float* __restrict__ src,
                                                           unsigned short* __restrict__ dst,
                                                           int R, int C)
{
    __shared__ unsigned short tile[64][72];
    src += (size_t)blockIdx.z * R * C;
    dst += (size_t)blockIdx.z * R * C;
    int r0 = blockIdx.y * 64, c0 = blockIdx.x * 64;
    int t = threadIdx.x;
    int tr = t >> 4;          // 0..15
    int tc = (t & 15) * 4;    // 0..60
    #pragma unroll
    for(int i=0;i<4;i++){
        float4 v = *(const float4*)&src[(size_t)(r0 + tr + i*16)*C + c0 + tc];
        tile[tc+0][tr + i*16] = f2bf(v.x);
        tile[tc+1][tr + i*16] = f2bf(v.y);
        tile[tc+2][tr + i*16] = f2bf(v.z);
        tile[tc+3][tr + i*16] = f2bf(v.w);
    }
    __syncthreads();
    int rr  = t >> 3;         // 0..31
    int cc8 = (t & 7) * 8;    // 0..56
    #pragma unroll
    for(int i=0;i<2;i++){
        u16x8 o = *(const u16x8*)&tile[rr + i*32][cc8];
        *(u16x8*)&dst[(size_t)(c0 + rr + i*32)*R + r0 + cc8] = o;
    }
}

// ---------------- gating (+ fused x fp32->bf16 convert) ----------------
__global__ __launch_bounds__(256) void k_gate(const float* __restrict__ x,
                                              const float* __restrict__ Wg,
                                              const float* __restrict__ bg,
                                              unsigned short* __restrict__ Xb,
                                              int* __restrict__ token_e,
                                              float* __restrict__ token_w,
                                              int* __restrict__ cnt)
{
    int tid = threadIdx.x;
    const float4* xs = (const float4*)x + (size_t)blockIdx.x * 1024;
    ushort4* xd = (ushort4*)Xb + (size_t)blockIdx.x * 1024;
    #pragma unroll
    for(int rep=0;rep<4;rep++){
        float4 v = xs[rep*256 + tid];
        ushort4 o; o.x=f2bf(v.x); o.y=f2bf(v.y); o.z=f2bf(v.z); o.w=f2bf(v.w);
        xd[rep*256 + tid] = o;
    }

    int wid = tid >> 6, lane = tid & 63;
    int t = blockIdx.x * 4 + wid;
    const float* xr = x + (size_t)t * DMODEL;
    float pe[NEXP];
    #pragma unroll
    for(int e=0;e<NEXP;e++) pe[e] = 0.f;
    for(int i=0;i<DMODEL/64;i++){
        int d = i*64 + lane;
        float xv = xr[d];
        const float* wr = Wg + (size_t)d * NEXP;
        #pragma unroll
        for(int e=0;e<NEXP;e++) pe[e] += xv * wr[e];
    }
    #pragma unroll
    for(int off=32; off>0; off>>=1){
        #pragma unroll
        for(int e=0;e<NEXP;e++) pe[e] += __shfl_xor(pe[e], off);
    }
    if(lane == 0){
        float lg[NEXP], mx = -1e30f;
        #pragma unroll
        for(int e=0;e<NEXP;e++){ lg[e] = pe[e] + bg[e]; mx = fmaxf(mx, lg[e]); }
        float pr[NEXP];
        #pragma unroll
        for(int e=0;e<NEXP;e++) pr[e] = expf(lg[e] - mx);
        int e0 = 0; float p0 = pr[0];
        #pragma unroll
        for(int e=1;e<NEXP;e++) if(pr[e] > p0){ p0 = pr[e]; e0 = e; }
        int e1 = -1; float p1 = -1.f;
        #pragma unroll
        for(int e=0;e<NEXP;e++) if(e != e0 && pr[e] > p1){ p1 = pr[e]; e1 = e; }
        float dn = p0 + p1;
        token_e[2*t]   = e0; token_w[2*t]   = p0/dn;
        token_e[2*t+1] = e1; token_w[2*t+1] = p1/dn;
        atomicAdd(&cnt[e0], 1); atomicAdd(&cnt[e1], 1);
    }
}

// ---------------- prefix + tile table + pad-fill + scatter (one block) ----------------
__global__ __launch_bounds__(256) void k_prefix_scatter(const int* __restrict__ cnt,
                                                        const int* __restrict__ token_e,
                                                        const float* __restrict__ token_w,
                                                        int* __restrict__ tile_e,
                                                        int* __restrict__ tile_row0,
                                                        int* __restrict__ tile_valid,
                                                        int* __restrict__ slot_token,
                                                        float* __restrict__ slot_w)
{
    __shared__ int sb[NEXP], scur[NEXP];
    int tid = threadIdx.x;
    if(tid == 0){
        int off = 0, nt = 0;
        for(int e=0;e<NEXP;e++){
            sb[e] = off; scur[e] = 0;
            int c = cnt[e];
            for(int r=0;r<c;r+=BM){
                tile_e[nt] = e; tile_row0[nt] = off + r;
                tile_valid[nt] = (c - r < BM) ? (c - r) : BM;
                nt++;
            }
            off += ((c + BM - 1)/BM)*BM;
        }
        for(int i=nt;i<MAXTILE;i++){ tile_e[i]=0; tile_row0[i]=0; tile_valid[i]=0; }
    }
    for(int s=tid; s<MAXSLOT; s+=256) slot_token[s] = 0;  // safe gather addr for pad rows
    __syncthreads();
    for(int i=tid; i<NSLOT; i+=256){
        int e = token_e[i];
        int s = sb[e] + atomicAdd(&scur[e], 1);
        slot_token[s] = i >> 1;
        slot_w[s] = token_w[i];
    }
}

// ---------------- grouped GEMM: 128x128 tile, double-buffered counted-vmcnt pipeline ----------------
// A: bf16, lda == K. GATHER: A row r -> slot_token[row0+r]. else A row = row0+r.
// B: bf16 [E][N][K] (pre-transposed).
// GELU: OutH[slot][N] = gelu(acc+bias) (bf16).  else: atomicAdd fp32 into
// outF[token][col] of slot_w[slot]*(acc+bias) — fused combine.
// LDS 32 KB: [buf:2][A|B][128 rows][32k] bf16; row = 64 B = 4 x 16B chunks.
// XOR swizzle: phys_chunk = log_chunk ^ ((row>>1)&3)  (involution; read phase = 2 lanes/granule, free).
template<bool GATHER, bool GELU>
__global__ __launch_bounds__(256) void k_gemm(const unsigned short* __restrict__ A,
                                              const unsigned short* __restrict__ Bw,
                                              const float* __restrict__ bias,
                                              const int* __restrict__ tile_e,
                                              const int* __restrict__ tile_row0,
                                              const int* __restrict__ tile_valid,
                                              const int* __restrict__ slot_token,
                                              const float* __restrict__ slot_w,
                                              unsigned short* __restrict__ OutH,
                                              float* __restrict__ outF,
                                              int K, int N)
{
    int tid = blockIdx.x;
    int valid = tile_valid[tid];
    if(valid == 0) return;
    int e = tile_e[tid];
    int row0 = tile_row0[tid];
    int n0 = blockIdx.y * BN;
    const unsigned short* Be = Bw + (size_t)e * N * K;

    __shared__ unsigned short lds[16384];   // 32 KB: buf*8192 + (A:0|B:4096) + row*32 + chunk*8

    int t = threadIdx.x;
    int lane = t & 63;
    int wid = t >> 6;
    int wr = wid >> 1, wc = wid & 1;

    // staging: thread t covers rows r0s=t>>2 and r0s+64; phys chunk pc = t&3.
    // source logical chunk = pc ^ ((r>>1)&3); (r>>1)&3 == (t>>3)&3 for both issues.
    int r0s = t >> 2;
    int csw = (t & 3) ^ ((t >> 3) & 3);
    const unsigned short* arow[2];
    const unsigned short* brow[2];
    #pragma unroll
    for(int i=0;i<2;i++){
        int r = i*64 + r0s;
        size_t aoff;
        if(GATHER) aoff = (size_t)slot_token[row0 + r] * (size_t)K;
        else       aoff = (size_t)(row0 + r) * (size_t)K;
        arow[i] = A  + aoff + csw*8;
        brow[i] = Be + (size_t)(n0 + r)*K + csw*8;
    }

#define STAGE(kt) { int bb = ((kt)&1)*8192; \
    gload16(arow[0] + (kt)*32, &lds[bb        + t*8]); \
    gload16(arow[1] + (kt)*32, &lds[bb + 2048 + t*8]); \
    gload16(brow[0] + (kt)*32, &lds[bb + 4096 + t*8]); \
    gload16(brow[1] + (kt)*32, &lds[bb + 6144 + t*8]); }

    f32x4 acc[4][4];
    #pragma unroll
    for(int m=0;m<4;m++)
        #pragma unroll
        for(int n=0;n<4;n++)
            acc[m][n] = (f32x4){0.f,0.f,0.f,0.f};

    int rl = lane & 15;
    int g  = lane >> 4;
    int swr = (g ^ ((rl >> 1) & 3)) * 8;    // per-lane swizzled chunk offset (shorts)

    // prologue: T0 -> buf0, T1 -> buf1; wait T0 landed (T1's 4 stay in flight)
    STAGE(0); STAGE(1);
    WAITVM4();
    __builtin_amdgcn_s_barrier();
    SCHEDPIN();

    int NK = K >> 5;
    for(int k=0;k<NK;k++){
        int bb = (k & 1) * 8192;
        bf16x8 af[4], bfv[4];
        #pragma unroll
        for(int m=0;m<4;m++) af[m]  = *(const bf16x8*)&lds[bb        + (wr*64 + m*16 + rl)*32 + swr];
        #pragma unroll
        for(int n=0;n<4;n++) bfv[n] = *(const bf16x8*)&lds[bb + 4096 + (wc*64 + n*16 + rl)*32 + swr];
        WAITLGKM();                          // this wave's reads complete (in regs)
        __builtin_amdgcn_s_barrier();        // all waves done reading buf(k&1)
        SCHEDPIN();
        if(k+2 < NK) STAGE(k+2);             // overwrite buf(k&1) for T(k+2)
        __builtin_amdgcn_s_setprio(1);
        #pragma unroll
        for(int m=0;m<4;m++)
            #pragma unroll
            for(int n=0;n<4;n++)
                acc[m][n] = MFMA16(af[m], bfv[n], acc[m][n]);
        __builtin_amdgcn_s_setprio(0);
        if(k+2 < NK)      { WAITVM4(); }     // T(k+1) landed; T(k+2)'s 4 in flight
        else if(k+1 < NK) { WAITVM0(); }     // tail: T(NK-1) landed
        __builtin_amdgcn_s_barrier();        // landing visible to all waves
        SCHEDPIN();
    }
#undef STAGE

    const float* be = bias + (size_t)e * N;
    #pragma unroll
    for(int m=0;m<4;m++){
        int rb = wr*64 + m*16 + g*4;
        #pragma unroll
        for(int j=0;j<4;j++){
            int r = rb + j;
            if(r >= valid) continue;
            size_t grow = (size_t)(row0 + r);
            if(GELU){
                #pragma unroll
                for(int n=0;n<4;n++){
                    int col = n0 + wc*64 + n*16 + rl;
                    float v = acc[m][n][j] + be[col];
                    v = 0.5f * v * (1.f + erff(v * 0.70710678118654752f));
                    OutH[grow * (size_t)N + col] = f2bf(v);
                }
            } else {
                float wsc = slot_w[grow];
                float* orow = outF + (size_t)slot_token[grow] * DMODEL;
                #pragma unroll
                for(int n=0;n<4;n++){
                    int col = n0 + wc*64 + n*16 + rl;
                    float v = (acc[m][n][j] + be[col]) * wsc;
                    atomicAdd(&orow[col], v);
                }
            }
        }
    }
}

extern "C" void kernel_launch(void* const* d_in, const int* in_sizes, int n_in,
                              void* d_out, int out_size, void* d_ws, size_t ws_size,
                              hipStream_t stream)
{
    const float* x  = (const float*)d_in[0];
    const float* W1 = (const float*)d_in[1];
    const float* b1 = (const float*)d_in[2];
    const float* W2 = (const float*)d_in[3];
    const float* b2 = (const float*)d_in[4];
    const float* Wg = (const float*)d_in[5];
    const float* bg = (const float*)d_in[6];
    float* out = (float*)d_out;

    char* p = (char*)d_ws;
    auto alloc = [&](size_t bytes)->char*{
        char* r = p; p += (bytes + 255) & ~(size_t)255; return r;
    };
    unsigned short* W1t = (unsigned short*)alloc((size_t)NEXP*DFF*DMODEL*2);   // [E][DFF][DMODEL]
    unsigned short* W2t = (unsigned short*)alloc((size_t)NEXP*DMODEL*DFF*2);   // [E][DMODEL][DFF]
    unsigned short* Xb  = (unsigned short*)alloc((size_t)NTOK*DMODEL*2);
    unsigned short* H   = (unsigned short*)alloc((size_t)MAXSLOT*DFF*2);
    int*   slot_token = (int*)alloc(MAXSLOT*4);
    float* slot_w     = (float*)alloc(MAXSLOT*4);
    int*   token_e    = (int*)alloc(NSLOT*4);
    float* token_w    = (float*)alloc(NSLOT*4);
    int*   cnt        = (int*)alloc(32);
    int*   tile_e     = (int*)alloc(MAXTILE*4);
    int*   tile_row0  = (int*)alloc(MAXTILE*4);
    int*   tile_valid = (int*)alloc(MAXTILE*4);
    (void)ws_size; (void)in_sizes; (void)n_in; (void)out_size;

    hipMemsetAsync(cnt, 0, 32, stream);
    hipMemsetAsync(out, 0, (size_t)NTOK*DMODEL*4, stream);   // fused-combine accumulator base
    k_gate<<<NTOK/4, 256, 0, stream>>>(x, Wg, bg, Xb, token_e, token_w, cnt);
    k_transpose_convert<<<dim3(DFF/64, DMODEL/64, NEXP), 256, 0, stream>>>(W1, W1t, DMODEL, DFF);
    k_transpose_convert<<<dim3(DMODEL/64, DFF/64, NEXP), 256, 0, stream>>>(W2, W2t, DFF, DMODEL);
    k_prefix_scatter<<<1, 256, 0, stream>>>(cnt, token_e, token_w,
                                            tile_e, tile_row0, tile_valid,
                                            slot_token, slot_w);
    k_gemm<true, true ><<<dim3(MAXTILE, DFF/BN),    256, 0, stream>>>(
        Xb, W1t, b1, tile_e, tile_row0, tile_valid, slot_token, slot_w, H, nullptr, DMODEL, DFF);
    k_gemm<false,false><<<dim3(MAXTILE, DMODEL/BN), 256, 0, stream>>>(
        H,  W2t, b2, tile_e, tile_row0, tile_valid, slot_token, slot_w, nullptr, out, DFF, DMODEL);
}

// Round 7
// 535.585 us; speedup vs baseline: 1.0463x; 1.0463x over previous
//
#include <hip/hip_runtime.h>
#include <hip/hip_bf16.h>

#define NTOK   4096
#define DMODEL 1024
#define DFF    4096
#define NEXP   8
#define TOPK   2
#define BM 128
#define BN 128
#define BK 64
#define NSLOT   (NTOK*TOPK)            // 8192
#define MAXSLOT (NSLOT + NEXP*BM)      // 9216
#define MAXTILE (MAXSLOT/BM)           // 72  (= 8 XCDs * 9)

typedef __attribute__((ext_vector_type(8))) short bf16x8;
typedef __attribute__((ext_vector_type(8))) unsigned short u16x8;
typedef __attribute__((ext_vector_type(4))) float f32x4;

__device__ __forceinline__ unsigned short f2bf(float f){
    union { float f; unsigned int u; } v; v.f = f;
    unsigned int r = (v.u + 0x7fffu + ((v.u >> 16) & 1u)) >> 16;
    return (unsigned short)r;
}

__device__ __forceinline__ void gload16(const unsigned short* g, unsigned short* l){
    __builtin_amdgcn_global_load_lds(
        (const __attribute__((address_space(1))) void*)g,
        (__attribute__((address_space(3))) void*)l,
        16, 0, 0);
}

#define WAITLGKM() asm volatile("s_waitcnt lgkmcnt(0)" ::: "memory")
#define WAITVM0()  asm volatile("s_waitcnt vmcnt(0)" ::: "memory")
#define SCHEDPIN() __builtin_amdgcn_sched_barrier(0)
#define MFMA16(a,b,c) __builtin_amdgcn_mfma_f32_16x16x32_bf16(a,b,c,0,0,0)

// ------ merged fp32 [R][C] -> bf16 [C][R] transpose-convert for W1 (z<8) and W2 (z>=8) ------
__global__ __launch_bounds__(256) void k_transpose_convert2(const float* __restrict__ W1,
                                                            const float* __restrict__ W2,
                                                            unsigned short* __restrict__ W1t,
                                                            unsigned short* __restrict__ W2t)
{
    __shared__ unsigned short tile[64][72];
    int z = blockIdx.z;
    const float* src; unsigned short* dst; int R, C, r0, c0;
    if(z < 8){
        src = W1  + (size_t)z * DMODEL * DFF;
        dst = W1t + (size_t)z * DMODEL * DFF;
        R = DMODEL; C = DFF;
        r0 = blockIdx.y * 64; c0 = blockIdx.x * 64;
    } else {
        src = W2  + (size_t)(z-8) * DFF * DMODEL;
        dst = W2t + (size_t)(z-8) * DFF * DMODEL;
        R = DFF; C = DMODEL;
        r0 = blockIdx.x * 64; c0 = blockIdx.y * 64;
    }
    int t = threadIdx.x;
    int tr = t >> 4;          // 0..15
    int tc = (t & 15) * 4;    // 0..60
    #pragma unroll
    for(int i=0;i<4;i++){
        float4 v = *(const float4*)&src[(size_t)(r0 + tr + i*16)*C + c0 + tc];
        tile[tc+0][tr + i*16] = f2bf(v.x);
        tile[tc+1][tr + i*16] = f2bf(v.y);
        tile[tc+2][tr + i*16] = f2bf(v.z);
        tile[tc+3][tr + i*16] = f2bf(v.w);
    }
    __syncthreads();
    int rr  = t >> 3;         // 0..31
    int cc8 = (t & 7) * 8;    // 0..56
    #pragma unroll
    for(int i=0;i<2;i++){
        u16x8 o = *(const u16x8*)&tile[rr + i*32][cc8];
        *(u16x8*)&dst[(size_t)(c0 + rr + i*32)*R + r0 + cc8] = o;
    }
}

// ---------------- gating (+ fused x fp32->bf16 convert) ----------------
__global__ __launch_bounds__(256) void k_gate(const float* __restrict__ x,
                                              const float* __restrict__ Wg,
                                              const float* __restrict__ bg,
                                              unsigned short* __restrict__ Xb,
                                              int* __restrict__ token_e,
                                              float* __restrict__ token_w,
                                              int* __restrict__ cnt)
{
    int tid = threadIdx.x;
    const float4* xs = (const float4*)x + (size_t)blockIdx.x * 1024;
    ushort4* xd = (ushort4*)Xb + (size_t)blockIdx.x * 1024;
    #pragma unroll
    for(int rep=0;rep<4;rep++){
        float4 v = xs[rep*256 + tid];
        ushort4 o; o.x=f2bf(v.x); o.y=f2bf(v.y); o.z=f2bf(v.z); o.w=f2bf(v.w);
        xd[rep*256 + tid] = o;
    }

    int wid = tid >> 6, lane = tid & 63;
    int t = blockIdx.x * 4 + wid;
    const float* xr = x + (size_t)t * DMODEL;
    float pe[NEXP];
    #pragma unroll
    for(int e=0;e<NEXP;e++) pe[e] = 0.f;
    for(int i=0;i<DMODEL/64;i++){
        int d = i*64 + lane;
        float xv = xr[d];
        const float* wr = Wg + (size_t)d * NEXP;
        #pragma unroll
        for(int e=0;e<NEXP;e++) pe[e] += xv * wr[e];
    }
    #pragma unroll
    for(int off=32; off>0; off>>=1){
        #pragma unroll
        for(int e=0;e<NEXP;e++) pe[e] += __shfl_xor(pe[e], off);
    }
    if(lane == 0){
        float lg[NEXP], mx = -1e30f;
        #pragma unroll
        for(int e=0;e<NEXP;e++){ lg[e] = pe[e] + bg[e]; mx = fmaxf(mx, lg[e]); }
        float pr[NEXP];
        #pragma unroll
        for(int e=0;e<NEXP;e++) pr[e] = expf(lg[e] - mx);
        int e0 = 0; float p0 = pr[0];
        #pragma unroll
        for(int e=1;e<NEXP;e++) if(pr[e] > p0){ p0 = pr[e]; e0 = e; }
        int e1 = -1; float p1 = -1.f;
        #pragma unroll
        for(int e=0;e<NEXP;e++) if(e != e0 && pr[e] > p1){ p1 = pr[e]; e1 = e; }
        float dn = p0 + p1;
        token_e[2*t]   = e0; token_w[2*t]   = p0/dn;
        token_e[2*t+1] = e1; token_w[2*t+1] = p1/dn;
        atomicAdd(&cnt[e0], 1); atomicAdd(&cnt[e1], 1);
    }
}

// ---------------- prefix + tile table + pad-fill + scatter (one block) ----------------
__global__ __launch_bounds__(256) void k_prefix_scatter(const int* __restrict__ cnt,
                                                        const int* __restrict__ token_e,
                                                        const float* __restrict__ token_w,
                                                        int* __restrict__ tile_e,
                                                        int* __restrict__ tile_row0,
                                                        int* __restrict__ tile_valid,
                                                        int* __restrict__ slot_token,
                                                        float* __restrict__ slot_w)
{
    __shared__ int sb[NEXP], scur[NEXP];
    int tid = threadIdx.x;
    if(tid == 0){
        int off = 0, nt = 0;
        for(int e=0;e<NEXP;e++){
            sb[e] = off; scur[e] = 0;
            int c = cnt[e];
            for(int r=0;r<c;r+=BM){
                tile_e[nt] = e; tile_row0[nt] = off + r;
                tile_valid[nt] = (c - r < BM) ? (c - r) : BM;
                nt++;
            }
            off += ((c + BM - 1)/BM)*BM;
        }
        for(int i=nt;i<MAXTILE;i++){ tile_e[i]=0; tile_row0[i]=0; tile_valid[i]=0; }
    }
    for(int s=tid; s<MAXSLOT; s+=256) slot_token[s] = 0;  // safe gather addr for pad rows
    __syncthreads();
    for(int i=tid; i<NSLOT; i+=256){
        int e = token_e[i];
        int s = sb[e] + atomicAdd(&scur[e], 1);
        slot_token[s] = i >> 1;
        slot_w[s] = token_w[i];
    }
}

// ---------------- grouped GEMM: 128x128, BK=64, minimum-2-phase double-buffer ----------------
// Recipe (T3 minimum, m230/m248): STAGE(k+1) first, ds_read buf(k), lgkmcnt(0),
// MFMA cluster (setprio), then ONE vmcnt(0) + ONE barrier per K-step.
// LDS 64 KB: [buf:2][A|B][128 rows][64k] bf16. 3-bit XOR chunk swizzle (proven R2/R5, 0 conflicts).
// XCD swizzle: blockIdx.x' = (x&7)*9 + x>>3  (72 = 8*9 bijective; y-stride 72 = 0 mod 8
// keeps the same A-panel on one XCD across all N-blocks).
template<bool GATHER, bool GELU>
__global__ __launch_bounds__(256, 2) void k_gemm(const unsigned short* __restrict__ A,
                                                 const unsigned short* __restrict__ Bw,
                                                 const float* __restrict__ bias,
                                                 const int* __restrict__ tile_e,
                                                 const int* __restrict__ tile_row0,
                                                 const int* __restrict__ tile_valid,
                                                 const int* __restrict__ slot_token,
                                                 const float* __restrict__ slot_w,
                                                 unsigned short* __restrict__ OutH,
                                                 float* __restrict__ outF,
                                                 int K, int N)
{
    int xb = blockIdx.x;
    int tid = (xb & 7) * (MAXTILE/8) + (xb >> 3);   // XCD-chunked bijective swizzle
    int valid = tile_valid[tid];
    if(valid == 0) return;
    int e = tile_e[tid];
    int row0 = tile_row0[tid];
    int n0 = blockIdx.y * BN;
    const unsigned short* Be = Bw + (size_t)e * N * K;

    __shared__ unsigned short lds[32768];   // 64 KB: buf*16384 + (A:0|B:8192) + chunk layout

    int t = threadIdx.x;
    int lane = t & 63;
    int wid = t >> 6;
    int wr = wid >> 1, wc = wid & 1;

    // staging: row r = i*32 + (t>>3) (i=0..3), phys chunk t&7; source chunk = (t&7) ^ (r&7).
    int srow = t >> 3;                      // 0..31
    int csw  = (t & 7) ^ (srow & 7);
    const unsigned short* arow[4];
    const unsigned short* brow[4];
    #pragma unroll
    for(int i=0;i<4;i++){
        int r = i*32 + srow;
        size_t aoff;
        if(GATHER) aoff = (size_t)slot_token[row0 + r] * (size_t)K;
        else       aoff = (size_t)(row0 + r) * (size_t)K;
        arow[i] = A  + aoff + csw*8;
        brow[i] = Be + (size_t)(n0 + r)*K + csw*8;
    }

#define STAGE(kt) { int bb = ((kt)&1)*16384; \
    gload16(arow[0] + (kt)*64, &lds[bb        + (0*256+t)*8]); \
    gload16(arow[1] + (kt)*64, &lds[bb        + (1*256+t)*8]); \
    gload16(arow[2] + (kt)*64, &lds[bb        + (2*256+t)*8]); \
    gload16(arow[3] + (kt)*64, &lds[bb        + (3*256+t)*8]); \
    gload16(brow[0] + (kt)*64, &lds[bb + 8192 + (0*256+t)*8]); \
    gload16(brow[1] + (kt)*64, &lds[bb + 8192 + (1*256+t)*8]); \
    gload16(brow[2] + (kt)*64, &lds[bb + 8192 + (2*256+t)*8]); \
    gload16(brow[3] + (kt)*64, &lds[bb + 8192 + (3*256+t)*8]); }

    f32x4 acc[4][4];
    #pragma unroll
    for(int m=0;m<4;m++)
        #pragma unroll
        for(int n=0;n<4;n++)
            acc[m][n] = (f32x4){0.f,0.f,0.f,0.f};

    int rl = lane & 15;
    int g  = lane >> 4;
    int rx = rl & 7;

    // prologue: T0 -> buf0, drained before first read
    STAGE(0);
    WAITVM0();
    __builtin_amdgcn_s_barrier();
    SCHEDPIN();

    int NK = K >> 6;
    for(int k=0;k<NK;k++){
        int bb = (k & 1) * 16384;
        if(k+1 < NK) STAGE(k+1);             // into other buffer (its readers finished last step)
        bf16x8 af[2][4], bfv[2][4];
        #pragma unroll
        for(int kb=0;kb<2;kb++){
            int sw = ((kb*4 + g) ^ rx) * 8;  // proven conflict-free swizzled chunk offset
            #pragma unroll
            for(int m=0;m<4;m++) af[kb][m]  = *(const bf16x8*)&lds[bb        + (wr*64 + m*16 + rl)*64 + sw];
            #pragma unroll
            for(int n=0;n<4;n++) bfv[kb][n] = *(const bf16x8*)&lds[bb + 8192 + (wc*64 + n*16 + rl)*64 + sw];
        }
        WAITLGKM();
        SCHEDPIN();                          // rule 18: keep MFMA below the lgkmcnt
        __builtin_amdgcn_s_setprio(1);
        #pragma unroll
        for(int kb=0;kb<2;kb++)
            #pragma unroll
            for(int m=0;m<4;m++)
                #pragma unroll
                for(int n=0;n<4;n++)
                    acc[m][n] = MFMA16(af[kb][m], bfv[kb][n], acc[m][n]);
        __builtin_amdgcn_s_setprio(0);
        WAITVM0();                           // T(k+1) landed; covered by ds_read+MFMA above
        __builtin_amdgcn_s_barrier();
        SCHEDPIN();
    }
#undef STAGE

    const float* be = bias + (size_t)e * N;
    #pragma unroll
    for(int m=0;m<4;m++){
        int rb = wr*64 + m*16 + g*4;
        #pragma unroll
        for(int j=0;j<4;j++){
            int r = rb + j;
            if(r >= valid) continue;
            size_t grow = (size_t)(row0 + r);
            if(GELU){
                #pragma unroll
                for(int n=0;n<4;n++){
                    int col = n0 + wc*64 + n*16 + rl;
                    float v = acc[m][n][j] + be[col];
                    v = 0.5f * v * (1.f + erff(v * 0.70710678118654752f));
                    OutH[grow * (size_t)N + col] = f2bf(v);
                }
            } else {
                float wsc = slot_w[grow];
                float* orow = outF + (size_t)slot_token[grow] * DMODEL;
                #pragma unroll
                for(int n=0;n<4;n++){
                    int col = n0 + wc*64 + n*16 + rl;
                    float v = (acc[m][n][j] + be[col]) * wsc;
                    atomicAdd(&orow[col], v);
                }
            }
        }
    }
}

extern "C" void kernel_launch(void* const* d_in, const int* in_sizes, int n_in,
                              void* d_out, int out_size, void* d_ws, size_t ws_size,
                              hipStream_t stream)
{
    const float* x  = (const float*)d_in[0];
    const float* W1 = (const float*)d_in[1];
    const float* b1 = (const float*)d_in[2];
    const float* W2 = (const float*)d_in[3];
    const float* b2 = (const float*)d_in[4];
    const float* Wg = (const float*)d_in[5];
    const float* bg = (const float*)d_in[6];
    float* out = (float*)d_out;

    char* p = (char*)d_ws;
    auto alloc = [&](size_t bytes)->char*{
        char* r = p; p += (bytes + 255) & ~(size_t)255; return r;
    };
    unsigned short* W1t = (unsigned short*)alloc((size_t)NEXP*DFF*DMODEL*2);   // [E][DFF][DMODEL]
    unsigned short* W2t = (unsigned short*)alloc((size_t)NEXP*DMODEL*DFF*2);   // [E][DMODEL][DFF]
    unsigned short* Xb  = (unsigned short*)alloc((size_t)NTOK*DMODEL*2);
    unsigned short* H   = (unsigned short*)alloc((size_t)MAXSLOT*DFF*2);
    int*   slot_token = (int*)alloc(MAXSLOT*4);
    float* slot_w     = (float*)alloc(MAXSLOT*4);
    int*   token_e    = (int*)alloc(NSLOT*4);
    float* token_w    = (float*)alloc(NSLOT*4);
    int*   cnt        = (int*)alloc(32);
    int*   tile_e     = (int*)alloc(MAXTILE*4);
    int*   tile_row0  = (int*)alloc(MAXTILE*4);
    int*   tile_valid = (int*)alloc(MAXTILE*4);
    (void)ws_size; (void)in_sizes; (void)n_in; (void)out_size;

    hipMemsetAsync(cnt, 0, 32, stream);
    hipMemsetAsync(out, 0, (size_t)NTOK*DMODEL*4, stream);   // fused-combine accumulator base
    k_gate<<<NTOK/4, 256, 0, stream>>>(x, Wg, bg, Xb, token_e, token_w, cnt);
    k_transpose_convert2<<<dim3(DFF/64, DMODEL/64, 16), 256, 0, stream>>>(W1, W2, W1t, W2t);
    k_prefix_scatter<<<1, 256, 0, stream>>>(cnt, token_e, token_w,
                                            tile_e, tile_row0, tile_valid,
                                            slot_token, slot_w);
    k_gemm<true, true ><<<dim3(MAXTILE, DFF/BN),    256, 0, stream>>>(
        Xb, W1t, b1, tile_e, tile_row0, tile_valid, slot_token, slot_w, H, nullptr, DMODEL, DFF);
    k_gemm<false,false><<<dim3(MAXTILE, DMODEL/BN), 256, 0, stream>>>(
        H,  W2t, b2, tile_e, tile_row0, tile_valid, slot_token, slot_w, nullptr, out, DFF, DMODEL);
}

// Round 8
// 481.062 us; speedup vs baseline: 1.1649x; 1.1133x over previous
//
#include <hip/hip_runtime.h>
#include <hip/hip_bf16.h>

#define NTOK   4096
#define DMODEL 1024
#define DFF    4096
#define NEXP   8
#define TOPK   2
#define BM 128
#define BN 128
#define BK 64
#define NSLOT   (NTOK*TOPK)            // 8192
#define MAXSLOT (NSLOT + NEXP*BM)      // 9216
#define MAXTILE (MAXSLOT/BM)           // 72 = 8 XCDs * 9

typedef __attribute__((ext_vector_type(8))) short bf16x8;
typedef __attribute__((ext_vector_type(8))) unsigned short u16x8;
typedef __attribute__((ext_vector_type(4))) float f32x4;

__device__ __forceinline__ unsigned short f2bf(float f){
    union { float f; unsigned int u; } v; v.f = f;
    unsigned int r = (v.u + 0x7fffu + ((v.u >> 16) & 1u)) >> 16;
    return (unsigned short)r;
}

__device__ __forceinline__ void gload16(const unsigned short* g, unsigned short* l){
    __builtin_amdgcn_global_load_lds(
        (const __attribute__((address_space(1))) void*)g,
        (__attribute__((address_space(3))) void*)l,
        16, 0, 0);
}

// ------ merged fp32 [R][C] -> bf16 [C][R] transpose-convert for W1 (z<8) and W2 (z>=8) ------
__global__ __launch_bounds__(256) void k_transpose_convert2(const float* __restrict__ W1,
                                                            const float* __restrict__ W2,
                                                            unsigned short* __restrict__ W1t,
                                                            unsigned short* __restrict__ W2t)
{
    __shared__ unsigned short tile[64][72];
    int z = blockIdx.z;
    const float* src; unsigned short* dst; int R, C, r0, c0;
    if(z < 8){
        src = W1  + (size_t)z * DMODEL * DFF;
        dst = W1t + (size_t)z * DMODEL * DFF;
        R = DMODEL; C = DFF;
        r0 = blockIdx.y * 64; c0 = blockIdx.x * 64;
    } else {
        src = W2  + (size_t)(z-8) * DFF * DMODEL;
        dst = W2t + (size_t)(z-8) * DFF * DMODEL;
        R = DFF; C = DMODEL;
        r0 = blockIdx.x * 64; c0 = blockIdx.y * 64;
    }
    int t = threadIdx.x;
    int tr = t >> 4;          // 0..15
    int tc = (t & 15) * 4;    // 0..60
    #pragma unroll
    for(int i=0;i<4;i++){
        float4 v = *(const float4*)&src[(size_t)(r0 + tr + i*16)*C + c0 + tc];
        tile[tc+0][tr + i*16] = f2bf(v.x);
        tile[tc+1][tr + i*16] = f2bf(v.y);
        tile[tc+2][tr + i*16] = f2bf(v.z);
        tile[tc+3][tr + i*16] = f2bf(v.w);
    }
    __syncthreads();
    int rr  = t >> 3;         // 0..31
    int cc8 = (t & 7) * 8;    // 0..56
    #pragma unroll
    for(int i=0;i<2;i++){
        u16x8 o = *(const u16x8*)&tile[rr + i*32][cc8];
        *(u16x8*)&dst[(size_t)(c0 + rr + i*32)*R + r0 + cc8] = o;
    }
}

// ---------------- gating (+ fused x fp32->bf16 convert) ----------------
__global__ __launch_bounds__(256) void k_gate(const float* __restrict__ x,
                                              const float* __restrict__ Wg,
                                              const float* __restrict__ bg,
                                              unsigned short* __restrict__ Xb,
                                              int* __restrict__ token_e,
                                              float* __restrict__ token_w,
                                              int* __restrict__ cnt)
{
    int tid = threadIdx.x;
    const float4* xs = (const float4*)x + (size_t)blockIdx.x * 1024;
    ushort4* xd = (ushort4*)Xb + (size_t)blockIdx.x * 1024;
    #pragma unroll
    for(int rep=0;rep<4;rep++){
        float4 v = xs[rep*256 + tid];
        ushort4 o; o.x=f2bf(v.x); o.y=f2bf(v.y); o.z=f2bf(v.z); o.w=f2bf(v.w);
        xd[rep*256 + tid] = o;
    }

    int wid = tid >> 6, lane = tid & 63;
    int t = blockIdx.x * 4 + wid;
    const float* xr = x + (size_t)t * DMODEL;
    float pe[NEXP];
    #pragma unroll
    for(int e=0;e<NEXP;e++) pe[e] = 0.f;
    for(int i=0;i<DMODEL/64;i++){
        int d = i*64 + lane;
        float xv = xr[d];
        const float* wr = Wg + (size_t)d * NEXP;
        #pragma unroll
        for(int e=0;e<NEXP;e++) pe[e] += xv * wr[e];
    }
    #pragma unroll
    for(int off=32; off>0; off>>=1){
        #pragma unroll
        for(int e=0;e<NEXP;e++) pe[e] += __shfl_xor(pe[e], off);
    }
    if(lane == 0){
        float lg[NEXP], mx = -1e30f;
        #pragma unroll
        for(int e=0;e<NEXP;e++){ lg[e] = pe[e] + bg[e]; mx = fmaxf(mx, lg[e]); }
        float pr[NEXP];
        #pragma unroll
        for(int e=0;e<NEXP;e++) pr[e] = expf(lg[e] - mx);
        int e0 = 0; float p0 = pr[0];
        #pragma unroll
        for(int e=1;e<NEXP;e++) if(pr[e] > p0){ p0 = pr[e]; e0 = e; }
        int e1 = -1; float p1 = -1.f;
        #pragma unroll
        for(int e=0;e<NEXP;e++) if(e != e0 && pr[e] > p1){ p1 = pr[e]; e1 = e; }
        float dn = p0 + p1;
        token_e[2*t]   = e0; token_w[2*t]   = p0/dn;
        token_e[2*t+1] = e1; token_w[2*t+1] = p1/dn;
        atomicAdd(&cnt[e0], 1); atomicAdd(&cnt[e1], 1);
    }
}

// ---------------- prefix + tile table + pad-fill + scatter (one block) ----------------
__global__ __launch_bounds__(256) void k_prefix_scatter(const int* __restrict__ cnt,
                                                        const int* __restrict__ token_e,
                                                        const float* __restrict__ token_w,
                                                        int* __restrict__ tile_e,
                                                        int* __restrict__ tile_row0,
                                                        int* __restrict__ tile_valid,
                                                        int* __restrict__ slot_token,
                                                        float* __restrict__ slot_w)
{
    __shared__ int sb[NEXP], scur[NEXP];
    int tid = threadIdx.x;
    if(tid == 0){
        int off = 0, nt = 0;
        for(int e=0;e<NEXP;e++){
            sb[e] = off; scur[e] = 0;
            int c = cnt[e];
            for(int r=0;r<c;r+=BM){
                tile_e[nt] = e; tile_row0[nt] = off + r;
                tile_valid[nt] = (c - r < BM) ? (c - r) : BM;
                nt++;
            }
            off += ((c + BM - 1)/BM)*BM;
        }
        for(int i=nt;i<MAXTILE;i++){ tile_e[i]=0; tile_row0[i]=0; tile_valid[i]=0; }
    }
    for(int s=tid; s<MAXSLOT; s+=256) slot_token[s] = 0;  // safe gather addr for pad rows
    __syncthreads();
    for(int i=tid; i<NSLOT; i+=256){
        int e = token_e[i];
        int s = sb[e] + atomicAdd(&scur[e], 1);
        slot_token[s] = i >> 1;
        slot_w[s] = token_w[i];
    }
}

// ---------------- grouped GEMM tile kernel (R5-proven m97 structure + XCD swizzle) ----------------
// A: bf16, lda == K. GATHER: A row r -> slot_token[row0+r]. else A row = row0+r.
// B: bf16 [E][N][K] (pre-transposed).
// GELU: OutH[slot][N] = gelu(acc+bias) (bf16).  else: atomicAdd fp32 into
// outF[token][col] of slot_w[slot]*(acc+bias) — fused combine.
template<bool GATHER, bool GELU>
__global__ __launch_bounds__(256, 3) void k_gemm(const unsigned short* __restrict__ A,
                                                 const unsigned short* __restrict__ Bw,
                                                 const float* __restrict__ bias,
                                                 const int* __restrict__ tile_e,
                                                 const int* __restrict__ tile_row0,
                                                 const int* __restrict__ tile_valid,
                                                 const int* __restrict__ slot_token,
                                                 const float* __restrict__ slot_w,
                                                 unsigned short* __restrict__ OutH,
                                                 float* __restrict__ outF,
                                                 int K, int N)
{
    int xb = blockIdx.x;
    int tid = (xb & 7) * (MAXTILE/8) + (xb >> 3);   // XCD-chunked bijective swizzle (72 = 8*9)
    int valid = tile_valid[tid];
    if(valid == 0) return;
    int e = tile_e[tid];
    int row0 = tile_row0[tid];
    int n0 = blockIdx.y * BN;
    const unsigned short* Be = Bw + (size_t)e * N * K;

    __shared__ unsigned short As[BM*BK];
    __shared__ unsigned short Bs[BN*BK];

    int t = threadIdx.x;
    int lane = t & 63;
    int wid = t >> 6;
    int wr = wid >> 1, wc = wid & 1;

    // staging: thread t, issue i stages LDS chunk p = i*256+t (16B chunks)
    // row r = i*32 + (t>>3), phys chunk c = t&7; content = global chunk c ^ (r&7)
    int srow = t >> 3;                      // 0..31
    int csw  = (t & 7) ^ (srow & 7);        // swizzled source chunk
    const unsigned short* arow[4];
    const unsigned short* brow[4];
    #pragma unroll
    for(int i=0;i<4;i++){
        int r = i*32 + srow;
        size_t aoff;
        if(GATHER) aoff = (size_t)slot_token[row0 + r] * (size_t)K;
        else       aoff = (size_t)(row0 + r) * (size_t)K;
        arow[i] = A  + aoff + csw*8;
        brow[i] = Be + (size_t)(n0 + r)*K + csw*8;
    }
    unsigned short* alds = As + (size_t)t * 8;
    unsigned short* blds = Bs + (size_t)t * 8;

    f32x4 acc[4][4];
    #pragma unroll
    for(int m=0;m<4;m++)
        #pragma unroll
        for(int n=0;n<4;n++)
            acc[m][n] = (f32x4){0.f,0.f,0.f,0.f};

    int rl = lane & 15;
    int g  = lane >> 4;
    int rx = rl & 7;

    for(int k0=0;k0<K;k0+=BK){
        __syncthreads();   // previous compute done before LDS overwrite
        #pragma unroll
        for(int i=0;i<4;i++){
            gload16(arow[i] + k0, alds + i*2048);
            gload16(brow[i] + k0, blds + i*2048);
        }
        __syncthreads();   // compiler drains vmcnt(0) before barrier -> tile ready

        #pragma unroll
        for(int kb=0;kb<2;kb++){
            int sw = ((kb*4 + g) ^ rx) * 8;   // swizzled chunk offset (shorts)
            bf16x8 af[4], bfv[4];
            #pragma unroll
            for(int m=0;m<4;m++) af[m]  = *(const bf16x8*)&As[(wr*64 + m*16 + rl)*BK + sw];
            #pragma unroll
            for(int n=0;n<4;n++) bfv[n] = *(const bf16x8*)&Bs[(wc*64 + n*16 + rl)*BK + sw];
            #pragma unroll
            for(int m=0;m<4;m++)
                #pragma unroll
                for(int n=0;n<4;n++)
                    acc[m][n] = __builtin_amdgcn_mfma_f32_16x16x32_bf16(af[m], bfv[n], acc[m][n], 0, 0, 0);
        }
    }

    const float* be = bias + (size_t)e * N;
    #pragma unroll
    for(int m=0;m<4;m++){
        int rb = wr*64 + m*16 + g*4;
        #pragma unroll
        for(int j=0;j<4;j++){
            int r = rb + j;
            if(r >= valid) continue;
            size_t grow = (size_t)(row0 + r);
            if(GELU){
                #pragma unroll
                for(int n=0;n<4;n++){
                    int col = n0 + wc*64 + n*16 + rl;
                    float v = acc[m][n][j] + be[col];
                    v = 0.5f * v * (1.f + erff(v * 0.70710678118654752f));
                    OutH[grow * (size_t)N + col] = f2bf(v);
                }
            } else {
                float wsc = slot_w[grow];
                float* orow = outF + (size_t)slot_token[grow] * DMODEL;
                #pragma unroll
                for(int n=0;n<4;n++){
                    int col = n0 + wc*64 + n*16 + rl;
                    float v = (acc[m][n][j] + be[col]) * wsc;
                    atomicAdd(&orow[col], v);
                }
            }
        }
    }
}

extern "C" void kernel_launch(void* const* d_in, const int* in_sizes, int n_in,
                              void* d_out, int out_size, void* d_ws, size_t ws_size,
                              hipStream_t stream)
{
    const float* x  = (const float*)d_in[0];
    const float* W1 = (const float*)d_in[1];
    const float* b1 = (const float*)d_in[2];
    const float* W2 = (const float*)d_in[3];
    const float* b2 = (const float*)d_in[4];
    const float* Wg = (const float*)d_in[5];
    const float* bg = (const float*)d_in[6];
    float* out = (float*)d_out;

    char* p = (char*)d_ws;
    auto alloc = [&](size_t bytes)->char*{
        char* r = p; p += (bytes + 255) & ~(size_t)255; return r;
    };
    unsigned short* W1t = (unsigned short*)alloc((size_t)NEXP*DFF*DMODEL*2);   // [E][DFF][DMODEL]
    unsigned short* W2t = (unsigned short*)alloc((size_t)NEXP*DMODEL*DFF*2);   // [E][DMODEL][DFF]
    unsigned short* Xb  = (unsigned short*)alloc((size_t)NTOK*DMODEL*2);
    unsigned short* H   = (unsigned short*)alloc((size_t)MAXSLOT*DFF*2);
    int*   slot_token = (int*)alloc(MAXSLOT*4);
    float* slot_w     = (float*)alloc(MAXSLOT*4);
    int*   token_e    = (int*)alloc(NSLOT*4);
    float* token_w    = (float*)alloc(NSLOT*4);
    int*   cnt        = (int*)alloc(32);
    int*   tile_e     = (int*)alloc(MAXTILE*4);
    int*   tile_row0  = (int*)alloc(MAXTILE*4);
    int*   tile_valid = (int*)alloc(MAXTILE*4);
    (void)ws_size; (void)in_sizes; (void)n_in; (void)out_size;

    hipMemsetAsync(cnt, 0, 32, stream);
    hipMemsetAsync(out, 0, (size_t)NTOK*DMODEL*4, stream);   // fused-combine accumulator base
    k_gate<<<NTOK/4, 256, 0, stream>>>(x, Wg, bg, Xb, token_e, token_w, cnt);
    k_transpose_convert2<<<dim3(DFF/64, DMODEL/64, 16), 256, 0, stream>>>(W1, W2, W1t, W2t);
    k_prefix_scatter<<<1, 256, 0, stream>>>(cnt, token_e, token_w,
                                            tile_e, tile_row0, tile_valid,
                                            slot_token, slot_w);
    k_gemm<true, true ><<<dim3(MAXTILE, DFF/BN),    256, 0, stream>>>(
        Xb, W1t, b1, tile_e, tile_row0, tile_valid, slot_token, slot_w, H, nullptr, DMODEL, DFF);
    k_gemm<false,false><<<dim3(MAXTILE, DMODEL/BN), 256, 0, stream>>>(
        H,  W2t, b2, tile_e, tile_row0, tile_valid, slot_token, slot_w, nullptr, out, DFF, DMODEL);
}